// Round 7
// baseline (205.521 us; speedup 1.0000x reference)
//
#include <hip/hip_runtime.h>
#include <stdint.h>

#define B_ 2
#define S_ 2048
#define E_ 1024
#define H_ 16
#define D_ 64
#define R_ 16

typedef short s16x8 __attribute__((ext_vector_type(8)));
typedef float f32x4 __attribute__((ext_vector_type(4)));

#define K1_ 0.045084220027780106f   // log2(e)/32
#define K0_ -28.853900817779268f    // -20*log2(e)

// fp32 -> bf16 bits, round-to-nearest (ties away)
__device__ __forceinline__ unsigned short f2bf(float f) {
  union { float f; unsigned u; } v; v.f = f;
  return (unsigned short)((v.u + 0x8000u) >> 16);
}

// async global->LDS, 16B per lane
__device__ __forceinline__ void load_lds16(const void* g, void* l) {
  __builtin_amdgcn_global_load_lds(
      (__attribute__((address_space(1))) void*)(g),
      (__attribute__((address_space(3))) void*)(l), 16, 0, 0);
}

// ---------------- prep, split into 4 kernels (pure code motion) ----------------

// x fp32 -> bf16. 4096 blocks.
__global__ void k_x2bf(const float* __restrict__ x, unsigned short* __restrict__ xb) {
  int i = (blockIdx.x * 256 + threadIdx.x) * 4;
  float4 v = *(const float4*)(x + i);
  ushort4 o;
  o.x = f2bf(v.x); o.y = f2bf(v.y); o.z = f2bf(v.z); o.w = f2bf(v.w);
  *(ushort4*)(xb + i) = o;
}

// Wq/Wk transpose -> Wt[(which,h,d),e] (Wq scaled by K1). 512 blocks.
__global__ void k_wtrans(const float* __restrict__ Wq, const float* __restrict__ Wk,
                         unsigned short* __restrict__ Wt) {
  __shared__ float T[64][65];
  const int bb = blockIdx.x;
  const int t = threadIdx.x;
  const int which = bb >> 8;
  const int h = (bb >> 4) & 15;
  const int et = bb & 15;
  const float scl = which ? 1.f : K1_;
  const float* src = (which ? Wk : Wq) + (h * E_ + et * 64) * D_;
#pragma unroll
  for (int pr = 0; pr < 4; ++pr) {
    const int row = pr * 16 + (t >> 4);
    const int col = (t & 15) * 4;
    float4 v = *(const float4*)(src + row * 64 + col);
    T[row][col] = v.x; T[row][col + 1] = v.y; T[row][col + 2] = v.z; T[row][col + 3] = v.w;
  }
  __syncthreads();
#pragma unroll
  for (int pr = 0; pr < 4; ++pr) {
    const int d = pr * 16 + (t >> 4);
    const int ec = (t & 15) * 4;
    ushort4 o;
    o.x = f2bf(T[ec][d] * scl); o.y = f2bf(T[ec + 1][d] * scl);
    o.z = f2bf(T[ec + 2][d] * scl); o.w = f2bf(T[ec + 3][d] * scl);
    *(ushort4*)(Wt + ((which << 10) + h * 64 + d) * 1024 + et * 64 + ec) = o;
  }
}

// fused Wv = Wvd@Wvu -> Wt[(2,h,d),e]. 4096 blocks.
__global__ void k_vfuse(const float* __restrict__ Wvd, const float* __restrict__ Wvu,
                        unsigned short* __restrict__ Wt) {
  const int idx = blockIdx.x * 256 + threadIdx.x;  // 1M
  const int row = idx >> 10;                        // h*64+d
  const int e = idx & 1023;
  const int h = row >> 6, d = row & 63;
  const float4* wd4 = (const float4*)(Wvd + (h << 14) + e * 16);
  const float* wu = Wvu + h * R_ * D_ + d;
  float acc = 0.f;
#pragma unroll
  for (int r4 = 0; r4 < 4; ++r4) {
    float4 a = wd4[r4];
    acc += a.x * wu[(r4 * 4 + 0) * 64];
    acc += a.y * wu[(r4 * 4 + 1) * 64];
    acc += a.z * wu[(r4 * 4 + 2) * 64];
    acc += a.w * wu[(r4 * 4 + 3) * 64];
  }
  Wt[(2048 + row) * 1024 + e] = f2bf(acc);
}

// biases (bq scaled by K1; bv fused through Wvu). 12 blocks.
__global__ void k_bias(const float* __restrict__ bq, const float* __restrict__ bk,
                       const float* __restrict__ bvd, const float* __restrict__ bvu,
                       const float* __restrict__ Wvu, float* __restrict__ ball) {
  int n = blockIdx.x * 256 + threadIdx.x;  // 3072
  int which = n >> 10;
  int hd = n & 1023;
  int h = hd >> 6, d = hd & 63;
  float v;
  if (which == 0) v = bq[hd] * K1_;
  else if (which == 1) v = bk[hd];
  else {
    v = bvu[hd];
#pragma unroll
    for (int r = 0; r < R_; ++r) v += bvd[h * R_ + r] * Wvu[(h * R_ + r) * D_ + d];
  }
  ball[n] = v;
}

// ---------------- fused QKV GEMM (R0-exact single-buffer, proven) ----------------
// cols [0,1024): Q*K1 -> (bh, s, d); [1024,2048): K -> (bh, s, d);
// [2048,3072): V -> transposed (bh, d, s)
__global__ __launch_bounds__(256, 2) void k_gemm_qkv(
    const unsigned short* __restrict__ X, const unsigned short* __restrict__ Wt,
    const float* __restrict__ ball,
    unsigned short* __restrict__ Qb, unsigned short* __restrict__ Kb,
    unsigned short* __restrict__ Vb) {
  __shared__ unsigned short As[128 * 32];
  __shared__ unsigned short Bs[128 * 32];
  const int tid = threadIdx.x;
  const int lane = tid & 63, wave = tid >> 6;
  const int quad = lane >> 4, l16 = lane & 15;
  const int mBase = blockIdx.y * 128, nBase = blockIdx.x * 128;
  const int wm = (wave & 1) * 64, wn = (wave >> 1) * 64;
  const int lrow = lane >> 2, lcol = (lane & 3) * 8;

  f32x4 acc[4][4];
#pragma unroll
  for (int mi = 0; mi < 4; ++mi)
#pragma unroll
    for (int ni = 0; ni < 4; ++ni) acc[mi][ni] = (f32x4){0.f, 0.f, 0.f, 0.f};

  for (int k0 = 0; k0 < E_; k0 += 32) {
#pragma unroll
    for (int i = 0; i < 2; ++i) {
      const int r0 = __builtin_amdgcn_readfirstlane((wave + i * 4) * 16);
      load_lds16(X + (mBase + r0 + lrow) * E_ + k0 + lcol, &As[r0 * 32]);
      load_lds16(Wt + (nBase + r0 + lrow) * E_ + k0 + lcol, &Bs[r0 * 32]);
    }
    __syncthreads();
    s16x8 af[4], bfr[4];
#pragma unroll
    for (int mi = 0; mi < 4; ++mi)
      af[mi] = *(const s16x8*)&As[(wm + mi * 16 + l16) * 32 + quad * 8];
#pragma unroll
    for (int ni = 0; ni < 4; ++ni)
      bfr[ni] = *(const s16x8*)&Bs[(wn + ni * 16 + l16) * 32 + quad * 8];
#pragma unroll
    for (int mi = 0; mi < 4; ++mi)
#pragma unroll
      for (int ni = 0; ni < 4; ++ni)
        acc[mi][ni] = __builtin_amdgcn_mfma_f32_16x16x32_bf16(af[mi], bfr[ni], acc[mi][ni], 0, 0, 0);
    __syncthreads();
  }

  const int which = nBase >> 10;  // uniform per block
#pragma unroll
  for (int ni = 0; ni < 4; ++ni) {
    const int n = nBase + wn + ni * 16 + l16;
    const int nh = n & 1023;
    const int h = nh >> 6, d = nh & 63;
    const float bias = ball[n];
#pragma unroll
    for (int mi = 0; mi < 4; ++mi) {
      const int m0 = mBase + wm + mi * 16 + quad * 4;
      const int b = m0 >> 11;
      const int s = m0 & 2047;
      const int bh = b * H_ + h;
      if (which == 2) {
        ushort4 pk;
        pk.x = f2bf(acc[mi][ni][0] + bias);
        pk.y = f2bf(acc[mi][ni][1] + bias);
        pk.z = f2bf(acc[mi][ni][2] + bias);
        pk.w = f2bf(acc[mi][ni][3] + bias);
        *(ushort4*)(Vb + (bh * D_ + d) * S_ + s) = pk;  // transposed store
      } else {
        unsigned short* dst = (which == 0 ? Qb : Kb) + (bh * S_ + s) * D_ + d;
#pragma unroll
        for (int r = 0; r < 4; ++r) dst[r * D_] = f2bf(acc[mi][ni][r] + bias);
      }
    }
  }
}

// ---------------- flash attention (R0-exact; now launched as 2 half-grids) ---
// anti-causal: attend t >= s. K AND V double-buffered in LDS via DMA; ONE
// barrier per tile, prefetch for kt+1 issued right after the barrier.
// Fixed-max softmax: Q pre-scaled by K1, QK C-initialized with K0.
// base = 0 or 512: half A covers bh 0..15 (chunks 0,1), half B bh 16..31.
__global__ __launch_bounds__(256, 4) void k_attn(
    const unsigned short* __restrict__ Qb, const unsigned short* __restrict__ Kb,
    const unsigned short* __restrict__ Vb, float* __restrict__ out, int base) {
  __shared__ unsigned short Ks[2][2 * 64 * 32];   // [buf][dhalf][64 k][32 d]
  __shared__ unsigned short Vs[2][2 * 64 * 32];   // [buf][thalf][64 d][32 t]
  __shared__ unsigned short Ps[4][16][40];        // [wave][q-row][32 t + pad]
  const int tid = threadIdx.x;
  const int lane = tid & 63, wave = tid >> 6;
  const int quad = lane >> 4, l16 = lane & 15;
  const int blk = base + blockIdx.x;
  const int chunk = blk >> 8;
  const int j = blk & 255;
  int qt = j >> 3;
  if (chunk & 1) qt = 31 - qt;
  const int bh = (j & 7) + 8 * chunk;
  const int q0 = qt * 64;
  const int lrow = lane >> 2, lcol = (lane & 3) * 8;
  const int r0 = __builtin_amdgcn_readfirstlane(wave * 16);
  const f32x4 kvec = {K0_, K0_, K0_, K0_};

  s16x8 qf[2];
  {
    const unsigned short* qp = Qb + (bh * S_ + q0 + wave * 16 + l16) * D_ + quad * 8;
    qf[0] = *(const s16x8*)qp;
    qf[1] = *(const s16x8*)(qp + 32);
  }
  f32x4 o[4];
#pragma unroll
  for (int dc = 0; dc < 4; ++dc) o[dc] = (f32x4){0.f, 0.f, 0.f, 0.f};
  float l_acc[4] = {0.f, 0.f, 0.f, 0.f};

#define DMA_KV(kt_, b_)                                                          \
  {                                                                              \
    _Pragma("unroll")                                                            \
    for (int hdc = 0; hdc < 2; ++hdc) {                                          \
      load_lds16(Kb + (bh * S_ + (kt_) * 64 + r0 + lrow) * D_ + hdc * 32 + lcol, \
                 &Ks[b_][hdc * 2048 + r0 * 32]);                                 \
      load_lds16(Vb + (bh * D_ + r0 + lrow) * S_ + (kt_) * 64 + hdc * 32 + lcol, \
                 &Vs[b_][hdc * 2048 + r0 * 32]);                                 \
    }                                                                            \
  }

  // prologue: stage tile qt into buffer 0
  DMA_KV(qt, 0);

  int buf = 0;
  for (int kt = qt; kt < S_ / 64; ++kt) {
    __syncthreads();  // Ks/Vs[buf] DMA drained; prior reads of buf^1 done
    if (kt + 1 < S_ / 64) DMA_KV(kt + 1, buf ^ 1);

    const bool diag = (kt == qt);
#pragma unroll
    for (int kc = 0; kc < 2; ++kc) {
      // scores for this 32-t half (tc = kc*2 + tcc), C-init with K0
#pragma unroll
      for (int tcc = 0; tcc < 2; ++tcc) {
        const int tc = kc * 2 + tcc;
        f32x4 a = __builtin_amdgcn_mfma_f32_16x16x32_bf16(
            qf[0], *(const s16x8*)&Ks[buf][(tc * 16 + l16) * 32 + quad * 8], kvec, 0, 0, 0);
        f32x4 sc = __builtin_amdgcn_mfma_f32_16x16x32_bf16(
            qf[1], *(const s16x8*)&Ks[buf][2048 + (tc * 16 + l16) * 32 + quad * 8], a, 0, 0, 0);
        if (diag) {
#pragma unroll
          for (int r = 0; r < 4; ++r) {
            const int t = tc * 16 + l16;
            const int q = wave * 16 + quad * 4 + r;
            if (t < q) sc[r] = -200.f;
          }
        }
#pragma unroll
        for (int r = 0; r < 4; ++r) {
          float p = exp2f(sc[r]);
          l_acc[r] += p;
          Ps[wave][quad * 4 + r][tcc * 16 + l16] =
              (unsigned short)(__float_as_uint(p) >> 16);
        }
      }
      // PV for this half: P A-frag from per-wave LDS (no barrier)
      s16x8 pf = *(const s16x8*)&Ps[wave][l16][quad * 8];
#pragma unroll
      for (int dc = 0; dc < 4; ++dc) {
        s16x8 vb = *(const s16x8*)&Vs[buf][kc * 2048 + (dc * 16 + l16) * 32 + quad * 8];
        o[dc] = __builtin_amdgcn_mfma_f32_16x16x32_bf16(pf, vb, o[dc], 0, 0, 0);
      }
    }
    buf ^= 1;
  }
#undef DMA_KV

  // epilogue: reduce l over the 16 lanes holding each row's t-slices
#pragma unroll
  for (int off = 1; off < 16; off <<= 1)
#pragma unroll
    for (int r = 0; r < 4; ++r) l_acc[r] += __shfl_xor(l_acc[r], off);
  float rinv[4];
#pragma unroll
  for (int r = 0; r < 4; ++r) rinv[r] = 1.f / l_acc[r];

  const int b = bh >> 4, h = bh & 15;
#pragma unroll
  for (int dc = 0; dc < 4; ++dc)
#pragma unroll
    for (int r = 0; r < 4; ++r) {
      const int s = q0 + wave * 16 + quad * 4 + r;
      out[(b * S_ + s) * (H_ * D_) + h * D_ + dc * 16 + l16] = o[dc][r] * rinv[r];
    }
}

// ---------------- launch ----------------

extern "C" void kernel_launch(void* const* d_in, const int* in_sizes, int n_in,
                              void* d_out, int out_size, void* d_ws, size_t ws_size,
                              hipStream_t stream) {
  const float* x   = (const float*)d_in[0];
  const float* Wq  = (const float*)d_in[1];
  const float* bq  = (const float*)d_in[2];
  const float* Wk  = (const float*)d_in[3];
  const float* bk  = (const float*)d_in[4];
  const float* Wvd = (const float*)d_in[5];
  const float* bvd = (const float*)d_in[6];
  const float* Wvu = (const float*)d_in[7];
  const float* bvu = (const float*)d_in[8];
  float* out = (float*)d_out;

  char* ws = (char*)d_ws;
  unsigned short* xb   = (unsigned short*)(ws);                    // 8 MB
  unsigned short* Wt   = (unsigned short*)(ws + (8u << 20));       // 6 MB
  float*          ball = (float*)(ws + (14u << 20));               // 12 KB
  unsigned short* Qb   = (unsigned short*)(ws + (15u << 20));      // 8 MB
  unsigned short* Kb   = (unsigned short*)(ws + (23u << 20));      // 8 MB
  unsigned short* Vb   = (unsigned short*)(ws + (31u << 20));      // 8 MB (transposed)

  // prep (4 independent kernels, pure code motion from k_prep)
  k_x2bf<<<4096, 256, 0, stream>>>(x, xb);
  k_wtrans<<<512, 256, 0, stream>>>(Wq, Wk, Wt);
  k_vfuse<<<4096, 256, 0, stream>>>(Wvd, Wvu, Wt);
  k_bias<<<12, 256, 0, stream>>>(bq, bk, bvd, bvu, Wvu, ball);

  k_gemm_qkv<<<dim3(3072 / 128, 4096 / 128), 256, 0, stream>>>(xb, Wt, ball, Qb, Kb, Vb);

  // attention in two half-grids (bh 0..15, then 16..31) to surface gemm/prep
  // in the top-5 profile table
  k_attn<<<512, 256, 0, stream>>>(Qb, Kb, Vb, out, 0);
  k_attn<<<512, 256, 0, stream>>>(Qb, Kb, Vb, out, 512);
}

// Round 9
// 183.525 us; speedup vs baseline: 1.1198x; 1.1198x over previous
//
#include <hip/hip_runtime.h>
#include <stdint.h>

#define B_ 2
#define S_ 2048
#define E_ 1024
#define H_ 16
#define D_ 64
#define R_ 16

typedef short s16x8 __attribute__((ext_vector_type(8)));
typedef float f32x4 __attribute__((ext_vector_type(4)));

#define K1_ 0.045084220027780106f   // log2(e)/32
#define K0_ -28.853900817779268f    // -20*log2(e)

// fp32 -> bf16 bits, round-to-nearest (ties away)
__device__ __forceinline__ unsigned short f2bf(float f) {
  union { float f; unsigned u; } v; v.f = f;
  return (unsigned short)((v.u + 0x8000u) >> 16);
}
__device__ __forceinline__ float bf2f(unsigned short b) {
  union { unsigned u; float f; } v; v.u = ((unsigned)b) << 16;
  return v.f;
}

// async global->LDS, 16B per lane
__device__ __forceinline__ void load_lds16(const void* g, void* l) {
  __builtin_amdgcn_global_load_lds(
      (__attribute__((address_space(1))) void*)(g),
      (__attribute__((address_space(3))) void*)(l), 16, 0, 0);
}

// ---------------- unified prep kernel ----------------
// blocks [0,4096): x fp32->bf16
// blocks [4096,4608): Wq/Wk transpose -> Wt[(which,h,d),e]  (Wq scaled by K1)
// blocks [4608,4864): Wvd transpose -> Wt[(2048 + h*16 + r), e]   (rank-16!)
// blocks [4864,4876): biases ball = {bq*K1 | bk | bvd}
__global__ void k_prep(const float* __restrict__ x,
                       const float* __restrict__ Wq, const float* __restrict__ Wk,
                       const float* __restrict__ Wvd,
                       const float* __restrict__ bq, const float* __restrict__ bk,
                       const float* __restrict__ bvd,
                       unsigned short* __restrict__ xb, unsigned short* __restrict__ Wt,
                       float* __restrict__ ball) {
  __shared__ float T[64][65];
  const int blk = blockIdx.x;
  const int t = threadIdx.x;
  if (blk < 4096) {
    int i = (blk * 256 + t) * 4;
    float4 v = *(const float4*)(x + i);
    ushort4 o;
    o.x = f2bf(v.x); o.y = f2bf(v.y); o.z = f2bf(v.z); o.w = f2bf(v.w);
    *(ushort4*)(xb + i) = o;
  } else if (blk < 4608) {
    const int bb = blk - 4096;
    const int which = bb >> 8;
    const int h = (bb >> 4) & 15;
    const int et = bb & 15;
    const float scl = which ? 1.f : K1_;
    const float* src = (which ? Wk : Wq) + (h * E_ + et * 64) * D_;
#pragma unroll
    for (int pr = 0; pr < 4; ++pr) {
      const int row = pr * 16 + (t >> 4);
      const int col = (t & 15) * 4;
      float4 v = *(const float4*)(src + row * 64 + col);
      T[row][col] = v.x; T[row][col + 1] = v.y; T[row][col + 2] = v.z; T[row][col + 3] = v.w;
    }
    __syncthreads();
#pragma unroll
    for (int pr = 0; pr < 4; ++pr) {
      const int d = pr * 16 + (t >> 4);
      const int ec = (t & 15) * 4;
      ushort4 o;
      o.x = f2bf(T[ec][d] * scl); o.y = f2bf(T[ec + 1][d] * scl);
      o.z = f2bf(T[ec + 2][d] * scl); o.w = f2bf(T[ec + 3][d] * scl);
      *(ushort4*)(Wt + ((which << 10) + h * 64 + d) * 1024 + et * 64 + ec) = o;
    }
  } else if (blk < 4864) {
    // Wvd[h][e][r] -> Wt[(2048 + h*16 + r)][e]   (256 rows x 1024)
    const int bb = blk - 4608;          // = h*16 + r
    const int h = bb >> 4, r = bb & 15;
    const int e0 = t * 4;
    const float* src = Wvd + (h << 14) + r;   // + e*16
    ushort4 o;
    o.x = f2bf(src[(e0 + 0) * 16]);
    o.y = f2bf(src[(e0 + 1) * 16]);
    o.z = f2bf(src[(e0 + 2) * 16]);
    o.w = f2bf(src[(e0 + 3) * 16]);
    *(ushort4*)(Wt + (2048 + bb) * 1024 + e0) = o;
  } else {
    int n = (blk - 4864) * 256 + t;  // 3072
    int which = n >> 10;
    int hd = n & 1023;
    if (which == 0) ball[n] = bq[hd] * K1_;
    else if (which == 1) ball[n] = bk[hd];
    else if (hd < 256) ball[2048 + hd] = bvd[hd];
  }
}

// ---------------- fused QKV GEMM (R0-proven structure; N shrunk to 2304) ------
// cols [0,1024): Q*K1 -> (bh, s, d); [1024,2048): K -> (bh, s, d);
// [2048,2304): vd = x@Wvd + bvd -> bf16 (bh, s, r)  [rank-16 down-projection]
__global__ __launch_bounds__(256, 2) void k_gemm_qkv(
    const unsigned short* __restrict__ X, const unsigned short* __restrict__ Wt,
    const float* __restrict__ ball,
    unsigned short* __restrict__ Qb, unsigned short* __restrict__ Kb,
    unsigned short* __restrict__ vd) {
  __shared__ unsigned short As[128 * 32];
  __shared__ unsigned short Bs[128 * 32];
  const int tid = threadIdx.x;
  const int lane = tid & 63, wave = tid >> 6;
  const int quad = lane >> 4, l16 = lane & 15;
  const int mBase = blockIdx.y * 128, nBase = blockIdx.x * 128;
  const int wm = (wave & 1) * 64, wn = (wave >> 1) * 64;
  const int lrow = lane >> 2, lcol = (lane & 3) * 8;

  f32x4 acc[4][4];
#pragma unroll
  for (int mi = 0; mi < 4; ++mi)
#pragma unroll
    for (int ni = 0; ni < 4; ++ni) acc[mi][ni] = (f32x4){0.f, 0.f, 0.f, 0.f};

  for (int k0 = 0; k0 < E_; k0 += 32) {
#pragma unroll
    for (int i = 0; i < 2; ++i) {
      const int r0 = __builtin_amdgcn_readfirstlane((wave + i * 4) * 16);
      load_lds16(X + (mBase + r0 + lrow) * E_ + k0 + lcol, &As[r0 * 32]);
      load_lds16(Wt + (nBase + r0 + lrow) * E_ + k0 + lcol, &Bs[r0 * 32]);
    }
    __syncthreads();
    s16x8 af[4], bfr[4];
#pragma unroll
    for (int mi = 0; mi < 4; ++mi)
      af[mi] = *(const s16x8*)&As[(wm + mi * 16 + l16) * 32 + quad * 8];
#pragma unroll
    for (int ni = 0; ni < 4; ++ni)
      bfr[ni] = *(const s16x8*)&Bs[(wn + ni * 16 + l16) * 32 + quad * 8];
#pragma unroll
    for (int mi = 0; mi < 4; ++mi)
#pragma unroll
      for (int ni = 0; ni < 4; ++ni)
        acc[mi][ni] = __builtin_amdgcn_mfma_f32_16x16x32_bf16(af[mi], bfr[ni], acc[mi][ni], 0, 0, 0);
    __syncthreads();
  }

  const int which = nBase >> 10;  // 0,1 -> Q/K ; 2 -> vd (nBase 2048 or 2176)
#pragma unroll
  for (int ni = 0; ni < 4; ++ni) {
    const int n = nBase + wn + ni * 16 + l16;
    const int nh = n & 1023;
    const float bias = ball[n];
#pragma unroll
    for (int mi = 0; mi < 4; ++mi) {
      const int m0 = mBase + wm + mi * 16 + quad * 4;
      const int b = m0 >> 11;
      const int s = m0 & 2047;
      if (which == 2) {
        const int h = nh >> 4, r = nh & 15;     // nh in [0,256)
        const int bh = b * H_ + h;
        unsigned short* dst = vd + (bh * S_ + s) * 16 + r;
#pragma unroll
        for (int rr = 0; rr < 4; ++rr) dst[rr * 16] = f2bf(acc[mi][ni][rr] + bias);
      } else {
        const int h = nh >> 6, d = nh & 63;
        const int bh = b * H_ + h;
        unsigned short* dst = (which == 0 ? Qb : Kb) + (bh * S_ + s) * D_ + d;
#pragma unroll
        for (int rr = 0; rr < 4; ++rr) dst[rr * D_] = f2bf(acc[mi][ni][rr] + bias);
      }
    }
  }
}

// ---------------- V up-projection: v = vd @ Wvu + bvu -> Vb (transposed) -----
// 2048 blocks = (bh, d); 256 threads x 8 consecutive s each.
// Reads vd rows (16 bf16 = 2 x b128), dots with Wvu[h][*][d] (16 scalars,
// wave-uniform -> L1 broadcast), writes Vb[(bh*D+d)*S + s] as one b128.
__global__ __launch_bounds__(256) void k_vup(
    const unsigned short* __restrict__ vd, const float* __restrict__ Wvu,
    const float* __restrict__ bvu, unsigned short* __restrict__ Vb) {
  const int blk = blockIdx.x;
  const int bh = blk >> 6, d = blk & 63;
  const int h = bh & 15;
  const int s0 = threadIdx.x * 8;
  float wu[16];
#pragma unroll
  for (int r = 0; r < 16; ++r) wu[r] = Wvu[(h * 16 + r) * 64 + d];
  const float bias = bvu[h * 64 + d];

  float accv[8];
#pragma unroll
  for (int j = 0; j < 8; ++j) accv[j] = bias;
  const s16x8* vp = (const s16x8*)(vd + (bh * S_ + s0) * 16);
#pragma unroll
  for (int j = 0; j < 8; ++j) {
    s16x8 a = vp[j * 2];
    s16x8 b = vp[j * 2 + 1];
#pragma unroll
    for (int r = 0; r < 8; ++r) {
      accv[j] += bf2f((unsigned short)a[r]) * wu[r];
      accv[j] += bf2f((unsigned short)b[r]) * wu[8 + r];
    }
  }
  ushort4 o0, o1;
  o0.x = f2bf(accv[0]); o0.y = f2bf(accv[1]); o0.z = f2bf(accv[2]); o0.w = f2bf(accv[3]);
  o1.x = f2bf(accv[4]); o1.y = f2bf(accv[5]); o1.z = f2bf(accv[6]); o1.w = f2bf(accv[7]);
  unsigned short* dst = Vb + (bh * D_ + d) * S_ + s0;
  *(ushort4*)(dst) = o0;
  *(ushort4*)(dst + 4) = o1;
}

// ---------------- flash attention (R0-exact, proven 53.0 us) -----------------
// anti-causal: attend t >= s. K AND V double-buffered in LDS via DMA; ONE
// barrier per tile, prefetch for kt+1 issued right after the barrier.
// Fixed-max softmax: Q pre-scaled by K1, QK C-initialized with K0.
__global__ __launch_bounds__(256, 4) void k_attn(
    const unsigned short* __restrict__ Qb, const unsigned short* __restrict__ Kb,
    const unsigned short* __restrict__ Vb, float* __restrict__ out) {
  __shared__ unsigned short Ks[2][2 * 64 * 32];   // [buf][dhalf][64 k][32 d]
  __shared__ unsigned short Vs[2][2 * 64 * 32];   // [buf][thalf][64 d][32 t]
  __shared__ unsigned short Ps[4][16][40];        // [wave][q-row][32 t + pad]
  const int tid = threadIdx.x;
  const int lane = tid & 63, wave = tid >> 6;
  const int quad = lane >> 4, l16 = lane & 15;
  const int chunk = blockIdx.x >> 8;
  const int j = blockIdx.x & 255;
  int qt = j >> 3;
  if (chunk & 1) qt = 31 - qt;
  const int bh = (j & 7) + 8 * chunk;
  const int q0 = qt * 64;
  const int lrow = lane >> 2, lcol = (lane & 3) * 8;
  const int r0 = __builtin_amdgcn_readfirstlane(wave * 16);
  const f32x4 kvec = {K0_, K0_, K0_, K0_};

  s16x8 qf[2];
  {
    const unsigned short* qp = Qb + (bh * S_ + q0 + wave * 16 + l16) * D_ + quad * 8;
    qf[0] = *(const s16x8*)qp;
    qf[1] = *(const s16x8*)(qp + 32);
  }
  f32x4 o[4];
#pragma unroll
  for (int dc = 0; dc < 4; ++dc) o[dc] = (f32x4){0.f, 0.f, 0.f, 0.f};
  float l_acc[4] = {0.f, 0.f, 0.f, 0.f};

#define DMA_KV(kt_, b_)                                                          \
  {                                                                              \
    _Pragma("unroll")                                                            \
    for (int hdc = 0; hdc < 2; ++hdc) {                                          \
      load_lds16(Kb + (bh * S_ + (kt_) * 64 + r0 + lrow) * D_ + hdc * 32 + lcol, \
                 &Ks[b_][hdc * 2048 + r0 * 32]);                                 \
      load_lds16(Vb + (bh * D_ + r0 + lrow) * S_ + (kt_) * 64 + hdc * 32 + lcol, \
                 &Vs[b_][hdc * 2048 + r0 * 32]);                                 \
    }                                                                            \
  }

  // prologue: stage tile qt into buffer 0
  DMA_KV(qt, 0);

  int buf = 0;
  for (int kt = qt; kt < S_ / 64; ++kt) {
    __syncthreads();  // Ks/Vs[buf] DMA drained; prior reads of buf^1 done
    if (kt + 1 < S_ / 64) DMA_KV(kt + 1, buf ^ 1);

    const bool diag = (kt == qt);
#pragma unroll
    for (int kc = 0; kc < 2; ++kc) {
      // scores for this 32-t half (tc = kc*2 + tcc), C-init with K0
#pragma unroll
      for (int tcc = 0; tcc < 2; ++tcc) {
        const int tc = kc * 2 + tcc;
        f32x4 a = __builtin_amdgcn_mfma_f32_16x16x32_bf16(
            qf[0], *(const s16x8*)&Ks[buf][(tc * 16 + l16) * 32 + quad * 8], kvec, 0, 0, 0);
        f32x4 sc = __builtin_amdgcn_mfma_f32_16x16x32_bf16(
            qf[1], *(const s16x8*)&Ks[buf][2048 + (tc * 16 + l16) * 32 + quad * 8], a, 0, 0, 0);
        if (diag) {
#pragma unroll
          for (int r = 0; r < 4; ++r) {
            const int t = tc * 16 + l16;
            const int q = wave * 16 + quad * 4 + r;
            if (t < q) sc[r] = -200.f;
          }
        }
#pragma unroll
        for (int r = 0; r < 4; ++r) {
          float p = exp2f(sc[r]);
          l_acc[r] += p;
          Ps[wave][quad * 4 + r][tcc * 16 + l16] =
              (unsigned short)(__float_as_uint(p) >> 16);
        }
      }
      // PV for this half: P A-frag from per-wave LDS (no barrier)
      s16x8 pf = *(const s16x8*)&Ps[wave][l16][quad * 8];
#pragma unroll
      for (int dc = 0; dc < 4; ++dc) {
        s16x8 vb = *(const s16x8*)&Vs[buf][kc * 2048 + (dc * 16 + l16) * 32 + quad * 8];
        o[dc] = __builtin_amdgcn_mfma_f32_16x16x32_bf16(pf, vb, o[dc], 0, 0, 0);
      }
    }
    buf ^= 1;
  }
#undef DMA_KV

  // epilogue: reduce l over the 16 lanes holding each row's t-slices
#pragma unroll
  for (int off = 1; off < 16; off <<= 1)
#pragma unroll
    for (int r = 0; r < 4; ++r) l_acc[r] += __shfl_xor(l_acc[r], off);
  float rinv[4];
#pragma unroll
  for (int r = 0; r < 4; ++r) rinv[r] = 1.f / l_acc[r];

  const int b = bh >> 4, h = bh & 15;
#pragma unroll
  for (int dc = 0; dc < 4; ++dc)
#pragma unroll
    for (int r = 0; r < 4; ++r) {
      const int s = q0 + wave * 16 + quad * 4 + r;
      out[(b * S_ + s) * (H_ * D_) + h * D_ + dc * 16 + l16] = o[dc][r] * rinv[r];
    }
}

// ---------------- launch ----------------

extern "C" void kernel_launch(void* const* d_in, const int* in_sizes, int n_in,
                              void* d_out, int out_size, void* d_ws, size_t ws_size,
                              hipStream_t stream) {
  const float* x   = (const float*)d_in[0];
  const float* Wq  = (const float*)d_in[1];
  const float* bq  = (const float*)d_in[2];
  const float* Wk  = (const float*)d_in[3];
  const float* bk  = (const float*)d_in[4];
  const float* Wvd = (const float*)d_in[5];
  const float* bvd = (const float*)d_in[6];
  const float* Wvu = (const float*)d_in[7];
  const float* bvu = (const float*)d_in[8];
  float* out = (float*)d_out;

  char* ws = (char*)d_ws;
  unsigned short* xb   = (unsigned short*)(ws);                    // 8 MB
  unsigned short* Wt   = (unsigned short*)(ws + (8u << 20));       // 4.7 MB (2304 rows)
  float*          ball = (float*)(ws + (14u << 20));               // 9.2 KB
  unsigned short* Qb   = (unsigned short*)(ws + (15u << 20));      // 8 MB
  unsigned short* Kb   = (unsigned short*)(ws + (23u << 20));      // 8 MB
  unsigned short* Vb   = (unsigned short*)(ws + (31u << 20));      // 8 MB (transposed)
  unsigned short* vd   = (unsigned short*)(ws + (39u << 20));      // 2 MB

  k_prep<<<4876, 256, 0, stream>>>(x, Wq, Wk, Wvd, bq, bk, bvd, xb, Wt, ball);
  k_gemm_qkv<<<dim3(2304 / 128, 4096 / 128), 256, 0, stream>>>(xb, Wt, ball, Qb, Kb, vd);
  k_vup<<<2048, 256, 0, stream>>>(vd, Wvu, bvu, Vb);
  k_attn<<<1024, 256, 0, stream>>>(Qb, Kb, Vb, out);
}